// Round 1
// baseline (2653.551 us; speedup 1.0000x reference)
//
#include <hip/hip_runtime.h>

// Problem constants (N=512, L=16384), chunking T=1024, P=16.
#define NDIM 512
#define LSEQ 16384
#define TCH  1024
#define PCH  16

// ---------------------------------------------------------------------------
// solve_cols: forward substitution, one wave per column.
// Block j < 512: solve M w = e_j  (M = I - dt/2 * A, lower triangular),
//                write Ab[:,j] = 2w - e_j.
// Block j == 512: solve M w = dt*B, write Bb = w.
// Lane-distributed w: w[r] holds row k = r*64 + lane.
// ---------------------------------------------------------------------------
__global__ __launch_bounds__(64) void solve_cols(const float* __restrict__ A,
                                                 const float* __restrict__ Bv,
                                                 float* __restrict__ Ab,
                                                 float* __restrict__ Bb)
{
    const int j = blockIdx.x;      // 0..512
    const int lane = threadIdx.x;  // 0..63
    const float DT  = 1.0f / (float)LSEQ;
    const float DT2 = 0.5f / (float)LSEQ;
    const bool isB = (j == NDIM);

    float w[8];
#pragma unroll
    for (int r = 0; r < 8; ++r) {
        int k = (r << 6) + lane;
        w[r] = isB ? DT * Bv[k] : ((k == j) ? 1.0f : 0.0f);
    }

#pragma unroll
    for (int r8 = 0; r8 < 8; ++r8) {
        for (int ii = 0; ii < 64; ++ii) {
            const int i = (r8 << 6) + ii;
            const float* arow = A + i * NDIM;
            // dot = sum_{k<i} A[i][k] * w[k]   (w slots k>=i hold rhs, masked out)
            float dot = 0.f;
#pragma unroll
            for (int r = 0; r < 8; ++r) {
                if (r < r8) dot += arow[(r << 6) + lane] * w[r];
            }
            {
                float a = arow[(r8 << 6) + lane];
                if (lane < ii) dot += a * w[r8];
            }
#pragma unroll
            for (int off = 32; off; off >>= 1) dot += __shfl_xor(dot, off, 64);
            // w_i = (rhs_i + dt2*dot) / M_ii ; M_ii = 1 - dt2*A[i][i]
            float mii = 1.0f - DT2 * arow[i];
            float wi  = (w[r8] + DT2 * dot) / mii;  // valid on owner lane only
            if (lane == ii) w[r8] = wi;
        }
    }

    if (!isB) {
#pragma unroll
        for (int r = 0; r < 8; ++r) {
            int i = (r << 6) + lane;
            Ab[i * NDIM + j] = 2.0f * w[r] - ((i == j) ? 1.0f : 0.0f);
        }
    } else {
#pragma unroll
        for (int r = 0; r < 8; ++r) Bb[(r << 6) + lane] = w[r];
    }
}

// ---------------------------------------------------------------------------
// init_small: V[:,0] = Bb ; Crows[0,:] = C ; Ht[:,0] = hidden_state
// ---------------------------------------------------------------------------
__global__ void init_small(const float* __restrict__ Bb, const float* __restrict__ C,
                           const float* __restrict__ hs, float* __restrict__ V,
                           float* __restrict__ Crows, float* __restrict__ Ht)
{
    int t = blockIdx.x * blockDim.x + threadIdx.x;
    if (t < NDIM) {
        V[t * TCH]     = Bb[t];
        Crows[t]       = C[t];
        Ht[t * (PCH + 1)] = hs[t];
    }
}

// ---------------------------------------------------------------------------
// mm64: D(MxN) = A(MxK) @ B(KxN), row-major with leading dims. K % 16 == 0.
// 64x64 tile, 256 threads, 4x4 micro-tile, K-step 16 via LDS.
// ---------------------------------------------------------------------------
__global__ __launch_bounds__(256) void mm64(
    const float* __restrict__ A, int lda,
    const float* __restrict__ B, int ldb,
    float* __restrict__ D, int ldd,
    int M, int N, int K)
{
    __shared__ float As[16][68];  // As[k][m], row stride 68 floats (16B-aligned rows)
    __shared__ float Bs[16][68];  // Bs[k][n]
    const int tid = threadIdx.x;
    const int tx = tid & 15, ty = tid >> 4;
    const int row0 = blockIdx.y * 64, col0 = blockIdx.x * 64;
    float acc[4][4] = {};

    for (int k0 = 0; k0 < K; k0 += 16) {
#pragma unroll
        for (int t = tid; t < 1024; t += 256) {   // A tile 64 rows x 16 k
            int r = t >> 4, c = t & 15;
            int gr = row0 + r;
            As[c][r] = (gr < M) ? A[gr * lda + k0 + c] : 0.f;
        }
#pragma unroll
        for (int t = tid; t < 1024; t += 256) {   // B tile 16 k x 64 cols
            int r = t >> 6, c = t & 63;
            int gc = col0 + c;
            Bs[r][c] = (gc < N) ? B[(k0 + r) * ldb + gc] : 0.f;
        }
        __syncthreads();
#pragma unroll
        for (int kk = 0; kk < 16; ++kk) {
            float a[4], b[4];
#pragma unroll
            for (int i = 0; i < 4; ++i) a[i] = As[kk][ty * 4 + i];
#pragma unroll
            for (int j2 = 0; j2 < 4; ++j2) b[j2] = Bs[kk][tx * 4 + j2];
#pragma unroll
            for (int i = 0; i < 4; ++i)
#pragma unroll
                for (int j2 = 0; j2 < 4; ++j2) acc[i][j2] += a[i] * b[j2];
        }
        __syncthreads();
    }
#pragma unroll
    for (int i = 0; i < 4; ++i) {
        int gr = row0 + ty * 4 + i;
        if (gr < M) {
#pragma unroll
            for (int j2 = 0; j2 < 4; ++j2) {
                int gc = col0 + tx * 4 + j2;
                if (gc < N) D[gr * ldd + gc] = acc[i][j2];
            }
        }
    }
}

// ---------------------------------------------------------------------------
// compute_k: kv[j] = sum_i C[i] * V[i*TCH + j]   (k_j = C . v_j)
// ---------------------------------------------------------------------------
__global__ void compute_k(const float* __restrict__ C, const float* __restrict__ V,
                          float* __restrict__ kv)
{
    int j = blockIdx.x * blockDim.x + threadIdx.x;
    if (j < TCH) {
        float s = 0.f;
        for (int i = 0; i < NDIM; ++i) s += C[i] * V[i * TCH + j];
        kv[j] = s;
    }
}

// ---------------------------------------------------------------------------
// build_U: U[i*PCH + p] = sum_s V[i*TCH + (TCH-1-s)] * x[p*TCH + s]
// ---------------------------------------------------------------------------
__global__ void build_U(const float* __restrict__ V, const float* __restrict__ x,
                        float* __restrict__ U)
{
    int e = blockIdx.x * blockDim.x + threadIdx.x;  // 0..8191
    int p = e & (PCH - 1);
    int i = e >> 4;
    const float* vrow = V + i * TCH;
    const float* xc = x + p * TCH;
    float s = 0.f;
    for (int r = 0; r < TCH; ++r) s += vrow[TCH - 1 - r] * xc[r];
    U[i * PCH + p] = s;
}

// ---------------------------------------------------------------------------
// scan_step: h_{p+1} = G h_p + u_p ; one wave per row. Ht is NDIM x (PCH+1).
// ---------------------------------------------------------------------------
__global__ __launch_bounds__(256) void scan_step(const float* __restrict__ G,
                                                 const float* __restrict__ U,
                                                 float* __restrict__ Ht, int p,
                                                 float* __restrict__ out_h)
{
    const int wid  = (blockIdx.x * blockDim.x + threadIdx.x) >> 6;  // row, 0..511
    const int lane = threadIdx.x & 63;
    const int PP = PCH + 1;
    const float* g = G + wid * NDIM;
    float sum = 0.f;
#pragma unroll
    for (int r = 0; r < 8; ++r) {
        int k = (r << 6) + lane;
        sum += g[k] * Ht[k * PP + p];
    }
#pragma unroll
    for (int off = 32; off; off >>= 1) sum += __shfl_xor(sum, off, 64);
    if (lane == 0) {
        float h = sum + U[wid * PCH + p];
        Ht[wid * PP + p + 1] = h;
        if (out_h) out_h[wid] = h;
    }
}

// ---------------------------------------------------------------------------
// finalize: y[p*TCH+s] = Yb[s*PCH+p] + sum_{d=0}^{s} kv[d]*x[p*TCH + s - d]
// ---------------------------------------------------------------------------
__global__ void finalize(const float* __restrict__ kv, const float* __restrict__ x,
                         const float* __restrict__ Yb, float* __restrict__ out)
{
    int t = blockIdx.x * blockDim.x + threadIdx.x;  // 0..LSEQ-1
    int p = t >> 10;          // TCH = 1024
    int s = t & (TCH - 1);
    const float* xc = x + p * TCH;
    float y = Yb[s * PCH + p];
    for (int d = 0; d <= s; ++d) y += kv[d] * xc[s - d];
    out[t] = y;
}

// ---------------------------------------------------------------------------
extern "C" void kernel_launch(void* const* d_in, const int* in_sizes, int n_in,
                              void* d_out, int out_size, void* d_ws, size_t ws_size,
                              hipStream_t stream)
{
    const float* x  = (const float*)d_in[0];   // in_x (16384)
    const float* hs = (const float*)d_in[1];   // hidden_state (512)
    const float* A  = (const float*)d_in[2];   // A (512*512)
    const float* Bv = (const float*)d_in[3];   // B (512)
    const float* C  = (const float*)d_in[4];   // C (512)
    float* out = (float*)d_out;                // [y (16384) | h_final (512)]

    float* ws     = (float*)d_ws;
    float* Ab     = ws;                         // 512*512
    float* G0     = Ab + NDIM * NDIM;           // 512*512
    float* G1     = G0 + NDIM * NDIM;           // 512*512
    float* V      = G1 + NDIM * NDIM;           // 512*1024 (col j = v_j)
    float* Crows  = V + NDIM * TCH;             // 1024*512 (row j = c_j)
    float* CrowsS = Crows + TCH * NDIM;         // 1024*512 (row j = c_{j+1})
    float* Bb     = CrowsS + TCH * NDIM;        // 512
    float* kv     = Bb + NDIM;                  // 1024
    float* U      = kv + TCH;                   // 512*16
    float* Ht     = U + NDIM * PCH;             // 512*17
    float* Yb     = Ht + NDIM * (PCH + 1);      // 1024*16

    solve_cols<<<NDIM + 1, 64, 0, stream>>>(A, Bv, Ab, Bb);
    init_small<<<2, 256, 0, stream>>>(Bb, C, hs, V, Crows, Ht);

    // Krylov doubling: after the loop g = Ab^TCH.
    const float* g = Ab;
    float* bufs[2] = {G0, G1};
    int idx = 0;
    for (int m = 1; m < TCH; m <<= 1) {
        // V[:, m:2m) = g @ V[:, :m)
        dim3 gv((m + 63) / 64, NDIM / 64);
        mm64<<<gv, 256, 0, stream>>>(g, NDIM, V, TCH, V + m, TCH, NDIM, m, NDIM);
        // Crows[m:2m, :] = Crows[:m, :] @ g
        dim3 gc(NDIM / 64, (m + 63) / 64);
        mm64<<<gc, 256, 0, stream>>>(Crows, NDIM, g, NDIM, Crows + m * NDIM, NDIM,
                                     m, NDIM, NDIM);
        // g' = g @ g
        dim3 gs(NDIM / 64, NDIM / 64);
        mm64<<<gs, 256, 0, stream>>>(g, NDIM, g, NDIM, bufs[idx], NDIM,
                                     NDIM, NDIM, NDIM);
        g = bufs[idx];
        idx ^= 1;
    }

    // CrowsS = Crows @ Ab  (rows -> c_1..c_TCH)
    mm64<<<dim3(NDIM / 64, TCH / 64), 256, 0, stream>>>(Crows, NDIM, Ab, NDIM,
                                                        CrowsS, NDIM, TCH, NDIM, NDIM);
    compute_k<<<TCH / 256, 256, 0, stream>>>(C, V, kv);
    build_U<<<(NDIM * PCH) / 256, 256, 0, stream>>>(V, x, U);

    // chunk scan: h_{p+1} = G h_p + u_p
    for (int p = 0; p < PCH; ++p)
        scan_step<<<(NDIM * 64) / 256, 256, 0, stream>>>(
            g, U, Ht, p, (p == PCH - 1) ? (out + LSEQ) : nullptr);

    // Yb[s, p] = c_{s+1} . h_p   =  CrowsS (TCH x 512) @ Ht[:, :PCH]
    mm64<<<dim3(1, TCH / 64), 256, 0, stream>>>(CrowsS, NDIM, Ht, PCH + 1,
                                                Yb, PCH, TCH, PCH, NDIM);
    finalize<<<LSEQ / 256, 256, 0, stream>>>(kv, x, Yb, out);
}

// Round 2
// 741.331 us; speedup vs baseline: 3.5794x; 3.5794x over previous
//
#include <hip/hip_runtime.h>

// N=512 state dim, L=16384 steps, chunk T=1024, P=16 chunks.
#define NDIM 512
#define LSEQ 16384
#define TCH  1024
#define PCH  16
#define HLD  20                      // Ht leading dim (mult of 4 for float4 align)

#define DTF  (1.0f/16384.0f)
#define DT2F (0.5f/16384.0f)

// ---------------------------------------------------------------------------
// mm_core: one 64x64 output tile of D = alpha * A(MxK) @ B(KxN). Row-major,
// runtime leading dims (all % 4 == 0 so float4 loads are 16B aligned).
// 256 threads, 4x4 micro-tile, K-step 16 via LDS, float4 staging + b128 reads.
// ---------------------------------------------------------------------------
__device__ __forceinline__ void mm_core(float (*As)[68], float (*Bs)[68],
    const float* __restrict__ A, int lda, const float* __restrict__ B, int ldb,
    float* __restrict__ D, int ldd, int M, int N, int K,
    int bx, int by, float alpha)
{
    const int tid = threadIdx.x;
    const int tx = tid & 15, ty = tid >> 4;
    const int row0 = by * 64, col0 = bx * 64;
    float acc[4][4] = {};

    for (int k0 = 0; k0 < K; k0 += 16) {
        {   // A tile: 64 rows x 16 k, one float4 per thread (transposed into As)
            int r = tid >> 2, cg = (tid & 3) * 4;
            int gr = row0 + r;
            float4 v = make_float4(0.f, 0.f, 0.f, 0.f);
            if (gr < M) v = *(const float4*)(A + (size_t)gr * lda + k0 + cg);
            As[cg + 0][r] = v.x; As[cg + 1][r] = v.y;
            As[cg + 2][r] = v.z; As[cg + 3][r] = v.w;
        }
        {   // B tile: 16 k x 64 cols, one float4 per thread
            int r = tid >> 4, cg = (tid & 15) * 4;
            int gc = col0 + cg;
            if (gc + 3 < N) {
                *(float4*)&Bs[r][cg] = *(const float4*)(B + (size_t)(k0 + r) * ldb + gc);
            } else {
#pragma unroll
                for (int t2 = 0; t2 < 4; ++t2)
                    Bs[r][cg + t2] = (gc + t2 < N) ? B[(size_t)(k0 + r) * ldb + gc + t2] : 0.f;
            }
        }
        __syncthreads();
#pragma unroll
        for (int kk = 0; kk < 16; ++kk) {
            float4 a = *(const float4*)&As[kk][ty * 4];
            float4 b = *(const float4*)&Bs[kk][tx * 4];
            acc[0][0] += a.x * b.x; acc[0][1] += a.x * b.y; acc[0][2] += a.x * b.z; acc[0][3] += a.x * b.w;
            acc[1][0] += a.y * b.x; acc[1][1] += a.y * b.y; acc[1][2] += a.y * b.z; acc[1][3] += a.y * b.w;
            acc[2][0] += a.z * b.x; acc[2][1] += a.z * b.y; acc[2][2] += a.z * b.z; acc[2][3] += a.z * b.w;
            acc[3][0] += a.w * b.x; acc[3][1] += a.w * b.y; acc[3][2] += a.w * b.z; acc[3][3] += a.w * b.w;
        }
        __syncthreads();
    }
#pragma unroll
    for (int i = 0; i < 4; ++i) {
        int gr = row0 + ty * 4 + i;
        if (gr < M) {
#pragma unroll
            for (int j = 0; j < 4; ++j) {
                int gc = col0 + tx * 4 + j;
                if (gc < N) D[(size_t)gr * ldd + gc] = alpha * acc[i][j];
            }
        }
    }
}

// ---------------------------------------------------------------------------
// diag_inv: invert the 8 diagonal 64x64 blocks of M = I - dt/2*A into W.
// One wave per block; lane j owns column j of the inverse in registers.
// Serial depth 64 (vs 512 for the full solve).
// ---------------------------------------------------------------------------
__global__ __launch_bounds__(64) void diag_inv(const float* __restrict__ A,
                                               float* __restrict__ W)
{
    __shared__ float sh[64][65];
    const int base = blockIdx.x * 64;
    const int lane = threadIdx.x;

    for (int r = 0; r < 64; ++r)
        sh[r][lane] = ((r == lane) ? 1.f : 0.f)
                    - DT2F * A[(size_t)(base + r) * NDIM + base + lane];
    __syncthreads();

    float xcol[64];
#pragma unroll
    for (int i = 0; i < 64; ++i) {
        float dot = 0.f;
#pragma unroll
        for (int k = 0; k < i; ++k) dot += sh[i][k] * xcol[k];
        // lanes j>i get dot==0 and delta==0 -> xcol[i]==0 automatically
        xcol[i] = (((lane == i) ? 1.f : 0.f) - dot) / sh[i][i];
    }
#pragma unroll
    for (int k = 0; k < 64; ++k)
        W[(size_t)(base + k) * NDIM + base + lane] = xcol[k];
}

// ---------------------------------------------------------------------------
// Off-diagonal doubling combine: for pair at offset o = z*2s,
//   tmp = A21 @ W11 ; W21 = dt/2 * W22 @ tmp     (since M21 = -dt/2*A21)
// ---------------------------------------------------------------------------
__global__ __launch_bounds__(256) void mm_pairA(const float* __restrict__ A,
    const float* __restrict__ W, float* __restrict__ T, int s)
{
    __shared__ float As[16][68], Bs[16][68];
    int o = blockIdx.z * 2 * s;
    mm_core(As, Bs, A + (size_t)(o + s) * NDIM + o, NDIM,
            W + (size_t)o * NDIM + o, NDIM,
            T + (size_t)(o + s) * NDIM + o, NDIM,
            s, s, s, blockIdx.x, blockIdx.y, 1.f);
}

__global__ __launch_bounds__(256) void mm_pairB(float* __restrict__ W,
    const float* __restrict__ T, int s)
{
    __shared__ float As[16][68], Bs[16][68];
    int o = blockIdx.z * 2 * s;
    mm_core(As, Bs, W + (size_t)(o + s) * NDIM + (o + s), NDIM,
            T + (size_t)(o + s) * NDIM + o, NDIM,
            W + (size_t)(o + s) * NDIM + o, NDIM,
            s, s, s, blockIdx.x, blockIdx.y, DT2F);
}

// ---------------------------------------------------------------------------
// form_ab: Ab = 2*W - I  (elementwise, float4)
// ---------------------------------------------------------------------------
__global__ __launch_bounds__(256) void form_ab(const float* __restrict__ W,
                                               float* __restrict__ Ab)
{
    int idx = blockIdx.x * 256 + threadIdx.x;       // 65536 float4 groups
    int i = idx >> 7, j0 = (idx & 127) << 2;
    float4 w = *(const float4*)(W + (size_t)i * NDIM + j0);
    float4 r = make_float4(2.f * w.x, 2.f * w.y, 2.f * w.z, 2.f * w.w);
    if (i == j0)          r.x -= 1.f;
    else if (i == j0 + 1) r.y -= 1.f;
    else if (i == j0 + 2) r.z -= 1.f;
    else if (i == j0 + 3) r.w -= 1.f;
    *(float4*)(Ab + (size_t)i * NDIM + j0) = r;
}

// ---------------------------------------------------------------------------
// prep: V[:,0] = Bb = dt * W @ Bv ; Crows[0,:] = C ; Ht[:,0] = hidden_state
// one wave per row.
// ---------------------------------------------------------------------------
__global__ __launch_bounds__(512) void prep(const float* __restrict__ W,
    const float* __restrict__ Bv, const float* __restrict__ C,
    const float* __restrict__ hs, float* __restrict__ V,
    float* __restrict__ Crows, float* __restrict__ Ht)
{
    const int w = threadIdx.x >> 6, lane = threadIdx.x & 63;
    const int i = blockIdx.x * 8 + w;
    float s = 0.f;
#pragma unroll
    for (int c = 0; c < 8; ++c) {
        int k = (c << 6) + lane;
        s += W[(size_t)i * NDIM + k] * Bv[k];
    }
#pragma unroll
    for (int off = 32; off; off >>= 1) s += __shfl_xor(s, off, 64);
    if (lane == 0) {
        V[(size_t)i * TCH] = DTF * s;
        Ht[i * HLD] = hs[i];
    }
    if (blockIdx.x == 0 && threadIdx.x < NDIM) Crows[threadIdx.x] = C[threadIdx.x];
}

// ---------------------------------------------------------------------------
// round_kernel: one Krylov-doubling round, 3 independent matmuls batched by z.
//  z=0: V[:, m:2m)    = g @ V[:, :m)
//  z=1: Crows[m:2m,:] = Crows[:m,:] @ g
//  z=2: gnew          = g @ g
// ---------------------------------------------------------------------------
__global__ __launch_bounds__(256) void round_kernel(const float* __restrict__ g,
    float* __restrict__ gnew, float* __restrict__ V, float* __restrict__ Crows, int m)
{
    __shared__ float As[16][68], Bs[16][68];
    const int z = blockIdx.z;
    const int nt = (m + 63) >> 6;
    if (z == 0) {
        if ((int)blockIdx.x >= nt) return;
        mm_core(As, Bs, g, NDIM, V, TCH, V + m, TCH,
                NDIM, m, NDIM, blockIdx.x, blockIdx.y, 1.f);
    } else if (z == 1) {
        if ((int)blockIdx.y >= nt) return;
        mm_core(As, Bs, Crows, NDIM, g, NDIM, Crows + (size_t)m * NDIM, NDIM,
                m, NDIM, NDIM, blockIdx.x, blockIdx.y, 1.f);
    } else {
        mm_core(As, Bs, g, NDIM, g, NDIM, gnew, NDIM,
                NDIM, NDIM, NDIM, blockIdx.x, blockIdx.y, 1.f);
    }
}

// ---------------------------------------------------------------------------
// post_kernel: z=0: CrowsS = Crows @ Ab ; z=1: kv = C @ V ; z=2: build U
// ---------------------------------------------------------------------------
__global__ __launch_bounds__(256) void post_kernel(const float* __restrict__ Crows,
    const float* __restrict__ Ab, float* __restrict__ CrowsS,
    const float* __restrict__ C, const float* __restrict__ V,
    const float* __restrict__ x, float* __restrict__ kv, float* __restrict__ U)
{
    __shared__ float As[16][68], Bs[16][68];
    const int z = blockIdx.z;
    if (z == 0) {
        mm_core(As, Bs, Crows, NDIM, Ab, NDIM, CrowsS, NDIM,
                TCH, NDIM, NDIM, blockIdx.x, blockIdx.y, 1.f);
    } else if (z == 1) {
        if (blockIdx.y != 0 || blockIdx.x >= 4) return;
        int j = blockIdx.x * 256 + threadIdx.x;      // 0..1023
        float s = 0.f;
        for (int i = 0; i < NDIM; ++i) s += C[i] * V[(size_t)i * TCH + j];
        kv[j] = s;
    } else {
        if (blockIdx.y >= 4) return;
        int e = ((int)(blockIdx.y * 8 + blockIdx.x)) * 256 + threadIdx.x;  // 0..8191
        int p = e & (PCH - 1);
        int i = e >> 4;
        const float* vrow = V + (size_t)i * TCH;
        const float* xc = x + p * TCH;
        float s = 0.f;
        for (int r = 0; r < TCH; ++r) s += vrow[TCH - 1 - r] * xc[r];
        U[i * PCH + p] = s;
    }
}

// ---------------------------------------------------------------------------
// scan_step: h_{p+1} = G h_p + u_p ; one wave per row. Ht is NDIM x HLD.
// ---------------------------------------------------------------------------
__global__ __launch_bounds__(256) void scan_step(const float* __restrict__ G,
                                                 const float* __restrict__ U,
                                                 float* __restrict__ Ht, int p,
                                                 float* __restrict__ out_h)
{
    const int wid  = (blockIdx.x * blockDim.x + threadIdx.x) >> 6;  // row, 0..511
    const int lane = threadIdx.x & 63;
    const float* g = G + (size_t)wid * NDIM;
    float sum = 0.f;
#pragma unroll
    for (int r = 0; r < 8; ++r) {
        int k = (r << 6) + lane;
        sum += g[k] * Ht[k * HLD + p];
    }
#pragma unroll
    for (int off = 32; off; off >>= 1) sum += __shfl_xor(sum, off, 64);
    if (lane == 0) {
        float h = sum + U[wid * PCH + p];
        Ht[wid * HLD + p + 1] = h;
        if (out_h) out_h[wid] = h;
    }
}

// ---------------------------------------------------------------------------
// mm64: standalone guarded tile GEMM (used for Yb)
// ---------------------------------------------------------------------------
__global__ __launch_bounds__(256) void mm64(const float* __restrict__ A, int lda,
    const float* __restrict__ B, int ldb, float* __restrict__ D, int ldd,
    int M, int N, int K, float alpha)
{
    __shared__ float As[16][68], Bs[16][68];
    mm_core(As, Bs, A, lda, B, ldb, D, ldd, M, N, K, blockIdx.x, blockIdx.y, alpha);
}

// ---------------------------------------------------------------------------
// finalize: y[p*TCH+s] = Yb[s*PCH+p] + sum_{d<=s} kv[d]*x[p*TCH + s - d]
// ---------------------------------------------------------------------------
__global__ __launch_bounds__(256) void finalize(const float* __restrict__ kv,
    const float* __restrict__ x, const float* __restrict__ Yb,
    float* __restrict__ out)
{
    int t = blockIdx.x * 256 + threadIdx.x;   // 0..LSEQ-1
    int p = t >> 10;
    int s = t & (TCH - 1);
    const float* xc = x + p * TCH;
    float y = Yb[s * PCH + p];
    for (int d = 0; d <= s; ++d) y += kv[d] * xc[s - d];
    out[t] = y;
}

// ---------------------------------------------------------------------------
extern "C" void kernel_launch(void* const* d_in, const int* in_sizes, int n_in,
                              void* d_out, int out_size, void* d_ws, size_t ws_size,
                              hipStream_t stream)
{
    const float* x  = (const float*)d_in[0];   // in_x (16384)
    const float* hs = (const float*)d_in[1];   // hidden_state (512)
    const float* A  = (const float*)d_in[2];   // A (512*512)
    const float* Bv = (const float*)d_in[3];   // B (512)
    const float* C  = (const float*)d_in[4];   // C (512)
    float* out = (float*)d_out;                // [y (16384) | h_final (512)]

    float* ws     = (float*)d_ws;
    float* Ab     = ws;                         // 512*512
    float* G0     = Ab + NDIM * NDIM;           // 512*512 (also T scratch)
    float* G1     = G0 + NDIM * NDIM;           // 512*512
    float* V      = G1 + NDIM * NDIM;           // 512*1024
    float* Crows  = V + NDIM * TCH;             // 1024*512
    float* CrowsS = Crows + TCH * NDIM;         // 1024*512 (first 512*512 doubles as W)
    float* kv     = CrowsS + TCH * NDIM;        // 1024
    float* U      = kv + TCH;                   // 512*16
    float* Ht     = U + NDIM * PCH;             // 512*HLD
    float* Yb     = Ht + NDIM * HLD;            // 1024*16

    // W aliases CrowsS: last read of W is in prep(); first write of CrowsS is
    // in post_kernel() — strictly later in stream order.
    float* W = CrowsS;
    float* T = G0;   // T last read in mm_pairB (level 3); G0 first written in round 1.

    hipMemsetAsync(W, 0, NDIM * NDIM * sizeof(float), stream);
    diag_inv<<<8, 64, 0, stream>>>(A, W);
    for (int s = 64; s <= 256; s <<= 1) {
        int np = NDIM / (2 * s);
        dim3 grid(s / 64, s / 64, np);
        mm_pairA<<<grid, 256, 0, stream>>>(A, W, T, s);
        mm_pairB<<<grid, 256, 0, stream>>>(W, T, s);
    }
    form_ab<<<256, 256, 0, stream>>>(W, Ab);
    prep<<<64, 512, 0, stream>>>(W, Bv, C, hs, V, Crows, Ht);

    const float* g = Ab;
    float* bufs[2] = {G0, G1};
    int idx = 0;
    for (int m = 1; m < TCH; m <<= 1) {
        round_kernel<<<dim3(8, 8, 3), 256, 0, stream>>>(g, bufs[idx], V, Crows, m);
        g = bufs[idx];
        idx ^= 1;
    }

    post_kernel<<<dim3(8, 16, 3), 256, 0, stream>>>(Crows, Ab, CrowsS, C, V, x, kv, U);

    for (int p = 0; p < PCH; ++p)
        scan_step<<<128, 256, 0, stream>>>(g, U, Ht, p,
                                           (p == PCH - 1) ? (out + LSEQ) : nullptr);

    mm64<<<dim3(1, 16), 256, 0, stream>>>(CrowsS, NDIM, Ht, HLD, Yb, PCH,
                                          TCH, PCH, NDIM, 1.f);
    finalize<<<LSEQ / 256, 256, 0, stream>>>(kv, x, Yb, out);
}

// Round 3
// 667.043 us; speedup vs baseline: 3.9781x; 1.1114x over previous
//
#include <hip/hip_runtime.h>

// N=512 state dim, L=16384 steps, chunk T=1024, P=16 chunks.
#define NDIM 512
#define LSEQ 16384
#define TCH  1024
#define PCH  16

#define DTF  (1.0f/16384.0f)
#define DT2F (0.5f/16384.0f)

// ---------------------------------------------------------------------------
// mm_tile: one 64x32 output tile of D = alpha * A(MxK) @ B(KxN). Row-major.
// 256 threads, 4x2 micro-tile, K-step 16 via LDS. 64x32 (not 64x64) so a
// 512x512 product yields 128 blocks -> 2x CU coverage; per-block 2.1 MFLOP.
// ---------------------------------------------------------------------------
__device__ __forceinline__ void mm_tile(float (*As)[68], float (*Bs)[36],
    const float* __restrict__ A, int lda, const float* __restrict__ B, int ldb,
    float* __restrict__ D, int ldd, int M, int N, int K,
    int bx, int by, float alpha)
{
    const int tid = threadIdx.x;
    const int tx = tid & 15;   // 16 col groups x2
    const int ty = tid >> 4;   // 16 row groups x4
    const int row0 = by * 64, col0 = bx * 32;
    float acc[4][2] = {};

    for (int k0 = 0; k0 < K; k0 += 16) {
        {   // A tile: 64 rows x 16 k (transposed into As), one float4/thread
            int r = tid >> 2, cg = (tid & 3) * 4;
            int gr = row0 + r;
            float4 v = make_float4(0.f, 0.f, 0.f, 0.f);
            if (gr < M) v = *(const float4*)(A + (size_t)gr * lda + k0 + cg);
            As[cg + 0][r] = v.x; As[cg + 1][r] = v.y;
            As[cg + 2][r] = v.z; As[cg + 3][r] = v.w;
        }
        if (tid < 128) {  // B tile: 16 k x 32 cols
            int r = tid >> 3, cg = (tid & 7) * 4;
            int gc = col0 + cg;
            const float* bp = B + (size_t)(k0 + r) * ldb;
            if (gc + 3 < N) {
                *(float4*)&Bs[r][cg] = *(const float4*)(bp + gc);
            } else {
#pragma unroll
                for (int t2 = 0; t2 < 4; ++t2)
                    Bs[r][cg + t2] = (gc + t2 < N) ? bp[gc + t2] : 0.f;
            }
        }
        __syncthreads();
#pragma unroll
        for (int kk = 0; kk < 16; ++kk) {
            float4 a = *(const float4*)&As[kk][ty * 4];
            float2 b = *(const float2*)&Bs[kk][tx * 2];
            acc[0][0] += a.x * b.x; acc[0][1] += a.x * b.y;
            acc[1][0] += a.y * b.x; acc[1][1] += a.y * b.y;
            acc[2][0] += a.z * b.x; acc[2][1] += a.z * b.y;
            acc[3][0] += a.w * b.x; acc[3][1] += a.w * b.y;
        }
        __syncthreads();
    }
#pragma unroll
    for (int i = 0; i < 4; ++i) {
        int gr = row0 + ty * 4 + i;
        if (gr < M) {
#pragma unroll
            for (int j = 0; j < 2; ++j) {
                int gc = col0 + tx * 2 + j;
                if (gc < N) D[(size_t)gr * ldd + gc] = alpha * acc[i][j];
            }
        }
    }
}

// ---------------------------------------------------------------------------
// diag_inv: invert the 8 diagonal 64x64 blocks of M = I - dt/2*A into W.
// ---------------------------------------------------------------------------
__global__ __launch_bounds__(64) void diag_inv(const float* __restrict__ A,
                                               float* __restrict__ W)
{
    __shared__ float sh[64][65];
    const int base = blockIdx.x * 64;
    const int lane = threadIdx.x;

    for (int r = 0; r < 64; ++r)
        sh[r][lane] = ((r == lane) ? 1.f : 0.f)
                    - DT2F * A[(size_t)(base + r) * NDIM + base + lane];
    __syncthreads();

    float xcol[64];
#pragma unroll
    for (int i = 0; i < 64; ++i) {
        float dot = 0.f;
#pragma unroll
        for (int k = 0; k < i; ++k) dot += sh[i][k] * xcol[k];
        xcol[i] = (((lane == i) ? 1.f : 0.f) - dot) / sh[i][i];
    }
#pragma unroll
    for (int k = 0; k < 64; ++k)
        W[(size_t)(base + k) * NDIM + base + lane] = xcol[k];
}

// ---------------------------------------------------------------------------
// Off-diagonal doubling combine: T = A21 @ W11 ; W21 = dt/2 * W22 @ T.
// ---------------------------------------------------------------------------
__global__ __launch_bounds__(256) void mm_pairA(const float* __restrict__ A,
    const float* __restrict__ W, float* __restrict__ T, int s)
{
    __shared__ float As[16][68]; __shared__ float Bs[16][36];
    int o = blockIdx.z * 2 * s;
    mm_tile(As, Bs, A + (size_t)(o + s) * NDIM + o, NDIM,
            W + (size_t)o * NDIM + o, NDIM,
            T + (size_t)(o + s) * NDIM + o, NDIM,
            s, s, s, blockIdx.x, blockIdx.y, 1.f);
}

__global__ __launch_bounds__(256) void mm_pairB(float* __restrict__ W,
    const float* __restrict__ T, int s)
{
    __shared__ float As[16][68]; __shared__ float Bs[16][36];
    int o = blockIdx.z * 2 * s;
    mm_tile(As, Bs, W + (size_t)(o + s) * NDIM + (o + s), NDIM,
            T + (size_t)(o + s) * NDIM + o, NDIM,
            W + (size_t)(o + s) * NDIM + o, NDIM,
            s, s, s, blockIdx.x, blockIdx.y, DT2F);
}

// ---------------------------------------------------------------------------
// form_ab: Ab = 2*W - I
// ---------------------------------------------------------------------------
__global__ __launch_bounds__(256) void form_ab(const float* __restrict__ W,
                                               float* __restrict__ Ab)
{
    int idx = blockIdx.x * 256 + threadIdx.x;
    int i = idx >> 7, j0 = (idx & 127) << 2;
    float4 w = *(const float4*)(W + (size_t)i * NDIM + j0);
    float4 r = make_float4(2.f * w.x, 2.f * w.y, 2.f * w.z, 2.f * w.w);
    if (i == j0)          r.x -= 1.f;
    else if (i == j0 + 1) r.y -= 1.f;
    else if (i == j0 + 2) r.z -= 1.f;
    else if (i == j0 + 3) r.w -= 1.f;
    *(float4*)(Ab + (size_t)i * NDIM + j0) = r;
}

// ---------------------------------------------------------------------------
// prep: V[:,0] = Bb = dt * W @ Bv ; Crows[0,:] = C. One wave per row.
// ---------------------------------------------------------------------------
__global__ __launch_bounds__(512) void prep(const float* __restrict__ W,
    const float* __restrict__ Bv, const float* __restrict__ C,
    float* __restrict__ V, float* __restrict__ Crows)
{
    const int w = threadIdx.x >> 6, lane = threadIdx.x & 63;
    const int i = blockIdx.x * 8 + w;
    float s = 0.f;
#pragma unroll
    for (int c = 0; c < 8; ++c) {
        int k = (c << 6) + lane;
        s += W[(size_t)i * NDIM + k] * Bv[k];
    }
#pragma unroll
    for (int off = 32; off; off >>= 1) s += __shfl_xor(s, off, 64);
    if (lane == 0) V[(size_t)i * TCH] = DTF * s;
    if (blockIdx.x == 0 && threadIdx.x < NDIM) Crows[threadIdx.x] = C[threadIdx.x];
}

// ---------------------------------------------------------------------------
// round_kernel: one Krylov-doubling round, grid (16,8,3).
//  z=0: V[:, m:2m) = g @ V[:, :m)      (skipped when m >= TCH)
//  z=1: Crows[m:2m,:] = Crows[:m,:] @ g (skipped when m >= TCH)
//  z=2: gnew = g @ g
// ---------------------------------------------------------------------------
__global__ __launch_bounds__(256) void round_kernel(const float* __restrict__ g,
    float* __restrict__ gnew, float* __restrict__ V, float* __restrict__ Crows, int m)
{
    __shared__ float As[16][68]; __shared__ float Bs[16][36];
    const int z = blockIdx.z, bx = blockIdx.x, by = blockIdx.y;
    if (z == 0) {
        if (m >= TCH) return;
        int ntx = (m + 31) >> 5; if (bx >= ntx) return;
        mm_tile(As, Bs, g, NDIM, V, TCH, V + m, TCH, NDIM, m, NDIM, bx, by, 1.f);
    } else if (z == 1) {
        if (m >= TCH) return;
        int nty = (m + 63) >> 6; if (by >= nty) return;
        mm_tile(As, Bs, Crows, NDIM, g, NDIM, Crows + (size_t)m * NDIM, NDIM,
                m, NDIM, NDIM, bx, by, 1.f);
    } else {
        mm_tile(As, Bs, g, NDIM, g, NDIM, gnew, NDIM,
                NDIM, NDIM, NDIM, bx, by, 1.f);
    }
}

// ---------------------------------------------------------------------------
// mm_plain: standalone tile GEMM (CrowsS = Crows @ Ab), grid (16,16).
// ---------------------------------------------------------------------------
__global__ __launch_bounds__(256) void mm_plain(const float* __restrict__ A, int lda,
    const float* __restrict__ B, int ldb, float* __restrict__ D, int ldd,
    int M, int N, int K)
{
    __shared__ float As[16][68]; __shared__ float Bs[16][36];
    mm_tile(As, Bs, A, lda, B, ldb, D, ldd, M, N, K, blockIdx.x, blockIdx.y, 1.f);
}

// ---------------------------------------------------------------------------
// kv_kernel: kv[j] = sum_i C[i] * V[i][j]. Block per 64 j's, 4 i-slabs.
// ---------------------------------------------------------------------------
__global__ __launch_bounds__(256) void kv_kernel(const float* __restrict__ C,
    const float* __restrict__ V, float* __restrict__ kv)
{
    __shared__ float sh[4][64];
    int jl = threadIdx.x & 63, slab = threadIdx.x >> 6;
    int j = blockIdx.x * 64 + jl;
    float s = 0.f;
    for (int r = 0; r < 128; ++r) {
        int i = slab * 128 + r;
        s += C[i] * V[(size_t)i * TCH + j];
    }
    sh[slab][jl] = s;
    __syncthreads();
    if (slab == 0) kv[j] = sh[0][jl] + sh[1][jl] + sh[2][jl] + sh[3][jl];
}

// ---------------------------------------------------------------------------
// build_u: U[p][i] = sum_r V[i][T-1-r] * x[p*T+r]  (+ G@h0 folded into p==0).
// One wave per (i,p); U stored 16 x 512 (scan layout).
// ---------------------------------------------------------------------------
__global__ __launch_bounds__(256) void build_u(const float* __restrict__ V,
    const float* __restrict__ x, const float* __restrict__ G,
    const float* __restrict__ hs, float* __restrict__ U)
{
    int wid = blockIdx.x * 4 + (threadIdx.x >> 6);   // 0..8191
    int lane = threadIdx.x & 63;
    int p = wid & (PCH - 1), i = wid >> 4;
    const float* vr = V + (size_t)i * TCH;
    const float* xc = x + p * TCH;
    float s = 0.f;
#pragma unroll
    for (int r = 0; r < 16; ++r) {
        int t = (r << 6) + lane;
        s += vr[TCH - 1 - t] * xc[t];
    }
    if (p == 0) {
        const float* gr = G + (size_t)i * NDIM;
#pragma unroll
        for (int r = 0; r < 8; ++r) {
            int k = (r << 6) + lane;
            s += gr[k] * hs[k];
        }
    }
#pragma unroll
    for (int off = 32; off; off >>= 1) s += __shfl_xor(s, off, 64);
    if (lane == 0) U[(size_t)p * NDIM + i] = s;
}

// ---------------------------------------------------------------------------
// scan_round: Kogge-Stone over 16 chunks. Znew[p] = Z[p] + G^o @ Z[p-o].
// Wave per (i,p). On the last round, also emit Hmat (h_0..h_15) and h_final.
// ---------------------------------------------------------------------------
__global__ __launch_bounds__(256) void scan_round(const float* __restrict__ G,
    const float* __restrict__ Zold, float* __restrict__ Znew,
    const float* __restrict__ hs, float* __restrict__ Hmat,
    float* __restrict__ hfin, int o, int last)
{
    int wid = blockIdx.x * 4 + (threadIdx.x >> 6);   // 0..8191
    int lane = threadIdx.x & 63;
    int p = wid & (PCH - 1), i = wid >> 4;
    float dot = 0.f;
    if (p >= o) {
        const float* gr = G + (size_t)i * NDIM;
        const float* zc = Zold + (size_t)(p - o) * NDIM;
#pragma unroll
        for (int r = 0; r < 8; ++r) {
            int k = (r << 6) + lane;
            dot += gr[k] * zc[k];
        }
#pragma unroll
        for (int off = 32; off; off >>= 1) dot += __shfl_xor(dot, off, 64);
    }
    if (lane == 0) {
        float z = Zold[(size_t)p * NDIM + i] + dot;
        Znew[(size_t)p * NDIM + i] = z;
        if (last) {
            if (p < PCH - 1) Hmat[(size_t)(p + 1) * NDIM + i] = z;
            else hfin[i] = z;
            if (p == 0) Hmat[i] = hs[i];
        }
    }
}

// ---------------------------------------------------------------------------
// yb_kernel: Yb[p][s] = CrowsS[s] . Hmat[p]. Wave per (s,p).
// ---------------------------------------------------------------------------
__global__ __launch_bounds__(256) void yb_kernel(const float* __restrict__ CrowsS,
    const float* __restrict__ Hmat, float* __restrict__ Yb)
{
    int wid = blockIdx.x * 4 + (threadIdx.x >> 6);   // 0..16383
    int lane = threadIdx.x & 63;
    int p = wid & (PCH - 1), s = wid >> 4;
    const float* cr = CrowsS + (size_t)s * NDIM;
    const float* hp = Hmat + (size_t)p * NDIM;
    float dot = 0.f;
#pragma unroll
    for (int r = 0; r < 8; ++r) {
        int k = (r << 6) + lane;
        dot += cr[k] * hp[k];
    }
#pragma unroll
    for (int off = 32; off; off >>= 1) dot += __shfl_xor(dot, off, 64);
    if (lane == 0) Yb[(size_t)p * TCH + s] = dot;
}

// ---------------------------------------------------------------------------
// finalize: y[p*T+s] = Yb[p][s] + sum_{j<=s} kv[s-j]*x[p*T+j], via LDS.
// 64 blocks: (chunk p, quarter q); s = q*256 + tid.
// ---------------------------------------------------------------------------
__global__ __launch_bounds__(256) void finalize(const float* __restrict__ kv,
    const float* __restrict__ x, const float* __restrict__ Yb,
    float* __restrict__ out)
{
    __shared__ float ks[TCH], xs[TCH];
    const int p = blockIdx.x >> 2, q = blockIdx.x & 3;
    const int tid = threadIdx.x;
    {
        const float4* xc = (const float4*)(x + p * TCH);
        const float4* kc = (const float4*)kv;
        ((float4*)ks)[tid] = kc[tid];
        ((float4*)xs)[tid] = xc[tid];
    }
    __syncthreads();
    const int s = q * 256 + tid;
    float y = Yb[(size_t)p * TCH + s];
    const int jmax = q * 256 + 255;
    for (int j = 0; j <= jmax; ++j) {
        if (j <= s) y += ks[s - j] * xs[j];
    }
    out[p * TCH + s] = y;
}

// ---------------------------------------------------------------------------
extern "C" void kernel_launch(void* const* d_in, const int* in_sizes, int n_in,
                              void* d_out, int out_size, void* d_ws, size_t ws_size,
                              hipStream_t stream)
{
    const float* x  = (const float*)d_in[0];
    const float* hs = (const float*)d_in[1];
    const float* A  = (const float*)d_in[2];
    const float* Bv = (const float*)d_in[3];
    const float* C  = (const float*)d_in[4];
    float* out = (float*)d_out;                 // [y (16384) | h_final (512)]

    const int MM = NDIM * NDIM;                 // 262144
    float* ws     = (float*)d_ws;
    float* Ab     = ws;                         // 1 MB
    float* P0     = Ab + MM;                    // g ping (aliases T scratch)
    float* P1     = P0 + MM;
    float* GA     = P1 + MM;                    // Ab^1024
    float* GB     = GA + MM;                    // Ab^2048
    float* GC     = GB + MM;                    // Ab^4096
    float* GD     = GC + MM;                    // Ab^8192
    float* V      = GD + MM;                    // 512 x 1024
    float* Crows  = V + NDIM * TCH;             // 1024 x 512
    float* CrowsS = Crows + TCH * NDIM;         // 1024 x 512 (first 1MB = W)
    float* kv     = CrowsS + TCH * NDIM;        // 1024
    float* U      = kv + TCH;                   // 16 x 512
    float* Z0     = U + PCH * NDIM;             // 16 x 512
    float* Z1     = Z0 + PCH * NDIM;            // 16 x 512
    float* Hmat   = Z1 + PCH * NDIM;            // 16 x 512
    float* Yb     = Hmat + PCH * NDIM;          // 16 x 1024

    float* W = CrowsS;  // W dead after prep(); CrowsS written later.
    float* T = P0;      // T dead after mm_pairB level 3; P0 written in round 1.

    // ---- W = (I - dt/2 A)^-1 via blocked inversion ----
    hipMemsetAsync(W, 0, MM * sizeof(float), stream);
    diag_inv<<<8, 64, 0, stream>>>(A, W);
    for (int s = 64; s <= 256; s <<= 1) {
        int np = NDIM / (2 * s);
        dim3 grid(s / 32, s / 64, np);
        mm_pairA<<<grid, 256, 0, stream>>>(A, W, T, s);
        mm_pairB<<<grid, 256, 0, stream>>>(W, T, s);
    }
    form_ab<<<256, 256, 0, stream>>>(W, Ab);
    prep<<<64, 512, 0, stream>>>(W, Bv, C, V, Crows);

    // ---- Krylov doubling (rounds 1..10) + 3 extra squarings for scan ----
    const float* g = Ab;
    float* gouts[13] = {P0, P1, P0, P1, P0, P1, P0, P1, P0, GA, GB, GC, GD};
    int m = 1;
    for (int r = 0; r < 13; ++r) {
        round_kernel<<<dim3(16, 8, 3), 256, 0, stream>>>(g, gouts[r], V, Crows, m);
        g = gouts[r];
        m <<= 1;
    }

    // ---- per-chunk pieces ----
    mm_plain<<<dim3(16, 16), 256, 0, stream>>>(Crows, NDIM, Ab, NDIM,
                                               CrowsS, NDIM, TCH, NDIM, NDIM);
    kv_kernel<<<16, 256, 0, stream>>>(C, V, kv);
    build_u<<<2048, 256, 0, stream>>>(V, x, GA, hs, U);

    // ---- Kogge-Stone scan over chunks: offsets 1,2,4,8 ----
    scan_round<<<2048, 256, 0, stream>>>(GA, U,  Z0, hs, Hmat, out + LSEQ, 1, 0);
    scan_round<<<2048, 256, 0, stream>>>(GB, Z0, Z1, hs, Hmat, out + LSEQ, 2, 0);
    scan_round<<<2048, 256, 0, stream>>>(GC, Z1, Z0, hs, Hmat, out + LSEQ, 4, 0);
    scan_round<<<2048, 256, 0, stream>>>(GD, Z0, Z1, hs, Hmat, out + LSEQ, 8, 1);

    // ---- epilogue ----
    yb_kernel<<<4096, 256, 0, stream>>>(CrowsS, Hmat, Yb);
    finalize<<<64, 256, 0, stream>>>(kv, x, Yb, out);
}

// Round 4
// 406.273 us; speedup vs baseline: 6.5314x; 1.6419x over previous
//
#include <hip/hip_runtime.h>

// N=512 state dim, L=16384 steps, chunk T=1024, P=16 chunks.
#define NDIM 512
#define LSEQ 16384
#define TCH  1024
#define PCH  16

#define DTF  (1.0f/16384.0f)
#define DT2F (0.5f/16384.0f)

// ---------------------------------------------------------------------------
// gkt_core: wave-task K-split GEMM. D(MxN) = alpha * A(MxK) @ B(KxN).
// Block = 256 threads = 4 waves; one 32x32 output tile per block; wave w
// computes the partial over k in [w*K/4, (w+1)*K/4) with private LDS staging
// (no cross-wave dependency in the K-loop), then one barrier + LDS reduce.
// Requires: M,N multiples of 32; K multiple of 64. Row pitch 36 floats keeps
// float4 LDS access 16B-aligned and conflicts <= 2-way (free, m136).
// smem: 4 regions x 1152 floats (As 16x36 | Bs 16x36; reused as 1024-f reduce).
// ---------------------------------------------------------------------------
__device__ __forceinline__ void gkt_core(float* __restrict__ smem,
    const float* __restrict__ A, int lda, const float* __restrict__ B, int ldb,
    float* __restrict__ D, int ldd, int ntx, int tile_id, int K, float alpha)
{
    const int tid  = threadIdx.x;
    const int w    = tid >> 6;
    const int lane = tid & 63;
    const int ty = lane >> 3, tx = lane & 7;          // 8x8 lane grid, 4x4 micro
    const int ty_t = tile_id / ntx, tx_t = tile_id % ntx;
    const int row0 = ty_t * 32, col0 = tx_t * 32;

    float* As = smem + w * 1152;          // As[k][r] = As[k*36 + r]
    float* Bs = As + 576;                 // Bs[k][c] = Bs[k*36 + c]

    const int Kc    = K >> 2;             // per-wave K chunk
    const int steps = Kc >> 4;            // k0 steps of 16
    const int kbase = w * Kc;

    float acc[4][4] = {};

    for (int s = 0; s < steps; ++s) {
        const int kb = kbase + s * 16;
        {   // stage A: As[k][r] = A[row0+r][kb+k]  (transpose), 2 float4/lane
#pragma unroll
            for (int i = 0; i < 2; ++i) {
                int idx = lane + 64 * i;
                int r = idx >> 2, cg = (idx & 3) * 4;
                float4 v = *(const float4*)(A + (size_t)(row0 + r) * lda + kb + cg);
                As[(cg + 0) * 36 + r] = v.x; As[(cg + 1) * 36 + r] = v.y;
                As[(cg + 2) * 36 + r] = v.z; As[(cg + 3) * 36 + r] = v.w;
            }
        }
        {   // stage B: Bs[k][c] = B[kb+k][col0+c], 2 float4/lane
#pragma unroll
            for (int i = 0; i < 2; ++i) {
                int idx = lane + 64 * i;
                int kr = idx >> 3, cg = (idx & 7) * 4;
                *(float4*)(Bs + kr * 36 + cg) =
                    *(const float4*)(B + (size_t)(kb + kr) * ldb + col0 + cg);
            }
        }
        __syncthreads();   // all waves have identical trip counts
#pragma unroll
        for (int kk = 0; kk < 16; ++kk) {
            float4 a = *(const float4*)(As + kk * 36 + 4 * ty);
            float4 b = *(const float4*)(Bs + kk * 36 + 4 * tx);
            acc[0][0] += a.x * b.x; acc[0][1] += a.x * b.y; acc[0][2] += a.x * b.z; acc[0][3] += a.x * b.w;
            acc[1][0] += a.y * b.x; acc[1][1] += a.y * b.y; acc[1][2] += a.y * b.z; acc[1][3] += a.y * b.w;
            acc[2][0] += a.z * b.x; acc[2][1] += a.z * b.y; acc[2][2] += a.z * b.z; acc[2][3] += a.z * b.w;
            acc[3][0] += a.w * b.x; acc[3][1] += a.w * b.y; acc[3][2] += a.w * b.z; acc[3][3] += a.w * b.w;
        }
        __syncthreads();
    }

    // write per-wave partial (32x32) into own region
    float* red = smem + w * 1152;
#pragma unroll
    for (int i = 0; i < 4; ++i)
        *(float4*)(red + (4 * ty + i) * 32 + 4 * tx) =
            make_float4(acc[i][0], acc[i][1], acc[i][2], acc[i][3]);
    __syncthreads();

    // cross-wave reduce: thread t sums float4 at offset t*4 over 4 regions
    float4 s0 = *(const float4*)(smem + 0 * 1152 + tid * 4);
    float4 s1 = *(const float4*)(smem + 1 * 1152 + tid * 4);
    float4 s2 = *(const float4*)(smem + 2 * 1152 + tid * 4);
    float4 s3 = *(const float4*)(smem + 3 * 1152 + tid * 4);
    float4 r4 = make_float4(alpha * (s0.x + s1.x + s2.x + s3.x),
                            alpha * (s0.y + s1.y + s2.y + s3.y),
                            alpha * (s0.z + s1.z + s2.z + s3.z),
                            alpha * (s0.w + s1.w + s2.w + s3.w));
    int r = tid >> 3, c = (tid & 7) * 4;
    *(float4*)(D + (size_t)(row0 + r) * ldd + col0 + c) = r4;
}

// ---------------------------------------------------------------------------
// mm_tile: legacy 64x32 tile (guarded dims) — only for tiny m<32 updates.
// ---------------------------------------------------------------------------
__device__ __forceinline__ void mm_tile(float* __restrict__ smem,
    const float* __restrict__ A, int lda, const float* __restrict__ B, int ldb,
    float* __restrict__ D, int ldd, int M, int N, int K,
    int bx, int by, float alpha)
{
    float (*As)[68] = (float (*)[68])smem;          // 16*68 = 1088 floats
    float (*Bs)[36] = (float (*)[36])(smem + 1088); // 16*36 = 576 floats
    const int tid = threadIdx.x;
    const int tx = tid & 15, ty = tid >> 4;
    const int row0 = by * 64, col0 = bx * 32;
    float acc[4][2] = {};

    for (int k0 = 0; k0 < K; k0 += 16) {
        {
            int r = tid >> 2, cg = (tid & 3) * 4;
            int gr = row0 + r;
            float4 v = make_float4(0.f, 0.f, 0.f, 0.f);
            if (gr < M) v = *(const float4*)(A + (size_t)gr * lda + k0 + cg);
            As[cg + 0][r] = v.x; As[cg + 1][r] = v.y;
            As[cg + 2][r] = v.z; As[cg + 3][r] = v.w;
        }
        if (tid < 128) {
            int r = tid >> 3, cg = (tid & 7) * 4;
            int gc = col0 + cg;
            const float* bp = B + (size_t)(k0 + r) * ldb;
            if (gc + 3 < N) {
                *(float4*)&Bs[r][cg] = *(const float4*)(bp + gc);
            } else {
#pragma unroll
                for (int t2 = 0; t2 < 4; ++t2)
                    Bs[r][cg + t2] = (gc + t2 < N) ? bp[gc + t2] : 0.f;
            }
        }
        __syncthreads();
#pragma unroll
        for (int kk = 0; kk < 16; ++kk) {
            float4 a = *(const float4*)&As[kk][ty * 4];
            float2 b = *(const float2*)&Bs[kk][tx * 2];
            acc[0][0] += a.x * b.x; acc[0][1] += a.x * b.y;
            acc[1][0] += a.y * b.x; acc[1][1] += a.y * b.y;
            acc[2][0] += a.z * b.x; acc[2][1] += a.z * b.y;
            acc[3][0] += a.w * b.x; acc[3][1] += a.w * b.y;
        }
        __syncthreads();
    }
#pragma unroll
    for (int i = 0; i < 4; ++i) {
        int gr = row0 + ty * 4 + i;
        if (gr < M) {
#pragma unroll
            for (int j = 0; j < 2; ++j) {
                int gc = col0 + tx * 2 + j;
                if (gc < N) D[(size_t)gr * ldd + gc] = alpha * acc[i][j];
            }
        }
    }
}

// ---------------------------------------------------------------------------
// diag_inv: invert the 8 diagonal 64x64 blocks of M = I - dt/2*A into W.
// ---------------------------------------------------------------------------
__global__ __launch_bounds__(64) void diag_inv(const float* __restrict__ A,
                                               float* __restrict__ W)
{
    __shared__ float sh[64][65];
    const int base = blockIdx.x * 64;
    const int lane = threadIdx.x;

    for (int r = 0; r < 64; ++r)
        sh[r][lane] = ((r == lane) ? 1.f : 0.f)
                    - DT2F * A[(size_t)(base + r) * NDIM + base + lane];
    __syncthreads();

    float xcol[64];
#pragma unroll
    for (int i = 0; i < 64; ++i) {
        float dot = 0.f;
#pragma unroll
        for (int k = 0; k < i; ++k) dot += sh[i][k] * xcol[k];
        xcol[i] = (((lane == i) ? 1.f : 0.f) - dot) / sh[i][i];
    }
#pragma unroll
    for (int k = 0; k < 64; ++k)
        W[(size_t)(base + k) * NDIM + base + lane] = xcol[k];
}

// ---------------------------------------------------------------------------
// pair combines: T = A21 @ W11 ; W21 = dt/2 * W22 @ T.  grid (tiles, npairs)
// ---------------------------------------------------------------------------
__global__ __launch_bounds__(256) void pairA2(const float* __restrict__ A,
    const float* __restrict__ W, float* __restrict__ T, int s)
{
    __shared__ float smem[4608];
    int o = blockIdx.y * 2 * s;
    gkt_core(smem, A + (size_t)(o + s) * NDIM + o, NDIM,
             W + (size_t)o * NDIM + o, NDIM,
             T + (size_t)(o + s) * NDIM + o, NDIM,
             s >> 5, blockIdx.x, s, 1.f);
}

__global__ __launch_bounds__(256) void pairB2(float* __restrict__ W,
    const float* __restrict__ T, int s)
{
    __shared__ float smem[4608];
    int o = blockIdx.y * 2 * s;
    gkt_core(smem, W + (size_t)(o + s) * NDIM + (o + s), NDIM,
             T + (size_t)(o + s) * NDIM + o, NDIM,
             W + (size_t)(o + s) * NDIM + o, NDIM,
             s >> 5, blockIdx.x, s, DT2F);
}

// ---------------------------------------------------------------------------
// form_ab: Ab = 2*W - I
// ---------------------------------------------------------------------------
__global__ __launch_bounds__(256) void form_ab(const float* __restrict__ W,
                                               float* __restrict__ Ab)
{
    int idx = blockIdx.x * 256 + threadIdx.x;
    int i = idx >> 7, j0 = (idx & 127) << 2;
    float4 w = *(const float4*)(W + (size_t)i * NDIM + j0);
    float4 r = make_float4(2.f * w.x, 2.f * w.y, 2.f * w.z, 2.f * w.w);
    if (i == j0)          r.x -= 1.f;
    else if (i == j0 + 1) r.y -= 1.f;
    else if (i == j0 + 2) r.z -= 1.f;
    else if (i == j0 + 3) r.w -= 1.f;
    *(float4*)(Ab + (size_t)i * NDIM + j0) = r;
}

// ---------------------------------------------------------------------------
// prep: Bb = dt * W @ Bv -> V[:,0] and contiguous Bbc ; Crows[0,:] = C.
// ---------------------------------------------------------------------------
__global__ __launch_bounds__(512) void prep(const float* __restrict__ W,
    const float* __restrict__ Bv, const float* __restrict__ C,
    float* __restrict__ V, float* __restrict__ Crows, float* __restrict__ Bbc)
{
    const int w = threadIdx.x >> 6, lane = threadIdx.x & 63;
    const int i = blockIdx.x * 8 + w;
    float s = 0.f;
#pragma unroll
    for (int c = 0; c < 8; ++c) {
        int k = (c << 6) + lane;
        s += W[(size_t)i * NDIM + k] * Bv[k];
    }
#pragma unroll
    for (int off = 32; off; off >>= 1) s += __shfl_xor(s, off, 64);
    if (lane == 0) {
        float bb = DTF * s;
        V[(size_t)i * TCH] = bb;
        Bbc[i] = bb;
    }
    if (blockIdx.x == 0 && threadIdx.x < NDIM) Crows[threadIdx.x] = C[threadIdx.x];
}

// ---------------------------------------------------------------------------
// round_kernel: one doubling round, grid (16,16,3).
//  z=2: gnew = g @ g                       (256 tiles, wave-task)
//  z=0: V[:, m:2m) = g @ V[:, :m)          (wave-task if m>=32, else legacy)
//  z=1: Crows[m:2m,:] = Crows[:m,:] @ g    (ditto)
// ---------------------------------------------------------------------------
__global__ __launch_bounds__(256) void round_kernel(const float* __restrict__ g,
    float* __restrict__ gnew, float* __restrict__ V, float* __restrict__ Crows, int m)
{
    __shared__ float smem[4608];
    const int z = blockIdx.z;
    const int tile_id = blockIdx.y * 16 + blockIdx.x;
    if (z == 2) {
        gkt_core(smem, g, NDIM, g, NDIM, gnew, NDIM, 16, tile_id, NDIM, 1.f);
    } else if (z == 0) {
        if (m >= TCH) return;
        if (m >= 32) {
            int ntx = m >> 5;
            if (tile_id >= (ntx << 4)) return;
            gkt_core(smem, g, NDIM, V, TCH, V + m, TCH, ntx, tile_id, NDIM, 1.f);
        } else {
            if (blockIdx.x != 0 || blockIdx.y >= 8) return;
            mm_tile(smem, g, NDIM, V, TCH, V + m, TCH,
                    NDIM, m, NDIM, 0, blockIdx.y, 1.f);
        }
    } else {
        if (m >= TCH) return;
        if (m >= 32) {
            int nty = m >> 5;
            if (tile_id >= (nty << 4)) return;
            gkt_core(smem, Crows, NDIM, g, NDIM, Crows + (size_t)m * NDIM, NDIM,
                     16, tile_id, NDIM, 1.f);
        } else {
            if (blockIdx.y != 0) return;
            mm_tile(smem, Crows, NDIM, g, NDIM, Crows + (size_t)m * NDIM, NDIM,
                    m, NDIM, NDIM, blockIdx.x, 0, 1.f);
        }
    }
}

// ---------------------------------------------------------------------------
// gemm_kt: standalone wave-task GEMM (CrowsS = Crows @ Ab). grid.x = tiles.
// ---------------------------------------------------------------------------
__global__ __launch_bounds__(256) void gemm_kt(const float* __restrict__ A, int lda,
    const float* __restrict__ B, int ldb, float* __restrict__ D, int ldd,
    int ntx, int K, float alpha)
{
    __shared__ float smem[4608];
    gkt_core(smem, A, lda, B, ldb, D, ldd, ntx, blockIdx.x, K, alpha);
}

// ---------------------------------------------------------------------------
// kv2: kv[j] = Crows[j] . Bb   (k_j = c_j . Bb). One wave per j.
// ---------------------------------------------------------------------------
__global__ __launch_bounds__(256) void kv2(const float* __restrict__ Crows,
    const float* __restrict__ Bbc, float* __restrict__ kv)
{
    int j = blockIdx.x * 4 + (threadIdx.x >> 6);
    int lane = threadIdx.x & 63;
    const float* cr = Crows + (size_t)j * NDIM;
    float dot = 0.f;
#pragma unroll
    for (int r = 0; r < 2; ++r) {
        int o = r * 256 + lane * 4;
        float4 c = *(const float4*)(cr + o);
        float4 b = *(const float4*)(Bbc + o);
        dot += c.x * b.x + c.y * b.y + c.z * b.z + c.w * b.w;
    }
#pragma unroll
    for (int off = 32; off; off >>= 1) dot += __shfl_xor(dot, off, 64);
    if (lane == 0) kv[j] = dot;
}

// ---------------------------------------------------------------------------
// build_u: U[p][i] = sum_r V[i][T-1-r]*x[p*T+r]  (+ GA@h0 folded into p==0).
// ---------------------------------------------------------------------------
__global__ __launch_bounds__(256) void build_u(const float* __restrict__ V,
    const float* __restrict__ x, const float* __restrict__ G,
    const float* __restrict__ hs, float* __restrict__ U)
{
    int wid = blockIdx.x * 4 + (threadIdx.x >> 6);   // 0..8191
    int lane = threadIdx.x & 63;
    int p = wid & (PCH - 1), i = wid >> 4;
    const float* vr = V + (size_t)i * TCH;
    const float* xc = x + p * TCH;
    float s = 0.f;
#pragma unroll
    for (int r = 0; r < 16; ++r) {
        int t = (r << 6) + lane;
        s += vr[TCH - 1 - t] * xc[t];
    }
    if (p == 0) {
        const float* gr = G + (size_t)i * NDIM;
#pragma unroll
        for (int r = 0; r < 8; ++r) {
            int k = (r << 6) + lane;
            s += gr[k] * hs[k];
        }
    }
#pragma unroll
    for (int off = 32; off; off >>= 1) s += __shfl_xor(s, off, 64);
    if (lane == 0) U[(size_t)p * NDIM + i] = s;
}

// ---------------------------------------------------------------------------
// scan_round: Kogge-Stone over 16 chunks. Znew[p] = Z[p] + G^o @ Z[p-o].
// ---------------------------------------------------------------------------
__global__ __launch_bounds__(256) void scan_round(const float* __restrict__ G,
    const float* __restrict__ Zold, float* __restrict__ Znew,
    const float* __restrict__ hs, float* __restrict__ Hmat,
    float* __restrict__ hfin, int o, int last)
{
    int wid = blockIdx.x * 4 + (threadIdx.x >> 6);
    int lane = threadIdx.x & 63;
    int p = wid & (PCH - 1), i = wid >> 4;
    float dot = 0.f;
    if (p >= o) {
        const float* gr = G + (size_t)i * NDIM;
        const float* zc = Zold + (size_t)(p - o) * NDIM;
#pragma unroll
        for (int r = 0; r < 8; ++r) {
            int k = (r << 6) + lane;
            dot += gr[k] * zc[k];
        }
#pragma unroll
        for (int off = 32; off; off >>= 1) dot += __shfl_xor(dot, off, 64);
    }
    if (lane == 0) {
        float z = Zold[(size_t)p * NDIM + i] + dot;
        Znew[(size_t)p * NDIM + i] = z;
        if (last) {
            if (p < PCH - 1) Hmat[(size_t)(p + 1) * NDIM + i] = z;
            else hfin[i] = z;
            if (p == 0) Hmat[i] = hs[i];
        }
    }
}

// ---------------------------------------------------------------------------
// emit: y[p*T+s] = CrowsS[s].Hmat[p] + sum_{t<=s} kv[s-t]*x[p*T+t].
// One wave per (p,s); 16384 waves / 4096 blocks.
// ---------------------------------------------------------------------------
__global__ __launch_bounds__(256) void emit(const float* __restrict__ CrowsS,
    const float* __restrict__ Hmat, const float* __restrict__ kv,
    const float* __restrict__ x, float* __restrict__ out)
{
    int wid = blockIdx.x * 4 + (threadIdx.x >> 6);   // 0..16383
    int lane = threadIdx.x & 63;
    int p = wid & (PCH - 1), s = wid >> 4;
    const float* cr = CrowsS + (size_t)s * NDIM;
    const float* hp = Hmat + (size_t)p * NDIM;
    float dot = 0.f;
#pragma unroll
    for (int r = 0; r < 2; ++r) {
        int o = r * 256 + lane * 4;
        float4 c = *(const float4*)(cr + o);
        float4 h = *(const float4*)(hp + o);
        dot += c.x * h.x + c.y * h.y + c.z * h.z + c.w * h.w;
    }
    const float* xc = x + p * TCH;
    int rmax = s >> 6;
    for (int r = 0; r <= rmax; ++r) {
        int t = (r << 6) + lane;
        if (t <= s) dot += kv[s - t] * xc[t];
    }
#pragma unroll
    for (int off = 32; off; off >>= 1) dot += __shfl_xor(dot, off, 64);
    if (lane == 0) out[p * TCH + s] = dot;
}

// ---------------------------------------------------------------------------
extern "C" void kernel_launch(void* const* d_in, const int* in_sizes, int n_in,
                              void* d_out, int out_size, void* d_ws, size_t ws_size,
                              hipStream_t stream)
{
    const float* x  = (const float*)d_in[0];
    const float* hs = (const float*)d_in[1];
    const float* A  = (const float*)d_in[2];
    const float* Bv = (const float*)d_in[3];
    const float* C  = (const float*)d_in[4];
    float* out = (float*)d_out;                 // [y (16384) | h_final (512)]

    const int MM = NDIM * NDIM;
    float* ws     = (float*)d_ws;
    float* Ab     = ws;
    float* P0     = Ab + MM;
    float* P1     = P0 + MM;
    float* GA     = P1 + MM;                    // Ab^1024
    float* GB     = GA + MM;                    // Ab^2048
    float* GC     = GB + MM;                    // Ab^4096
    float* GD     = GC + MM;                    // Ab^8192
    float* V      = GD + MM;                    // 512 x 1024
    float* Crows  = V + NDIM * TCH;             // 1024 x 512
    float* CrowsS = Crows + TCH * NDIM;         // 1024 x 512 (first 1MB = W)
    float* kv     = CrowsS + TCH * NDIM;        // 1024
    float* Bbc    = kv + TCH;                   // 512
    float* U      = Bbc + NDIM;                 // 16 x 512
    float* Z0     = U + PCH * NDIM;             // 16 x 512
    float* Z1     = Z0 + PCH * NDIM;            // 16 x 512
    float* Hmat   = Z1 + PCH * NDIM;            // 16 x 512

    float* W = CrowsS;  // W dead after prep(); CrowsS written later.
    float* T = P0;      // T dead after pairB2 level 3; P0 written in round 1.

    // ---- W = (I - dt/2 A)^-1 via blocked inversion ----
    hipMemsetAsync(W, 0, MM * sizeof(float), stream);
    diag_inv<<<8, 64, 0, stream>>>(A, W);
    for (int s = 64; s <= 256; s <<= 1) {
        int np = NDIM / (2 * s);
        int tiles = (s >> 5) * (s >> 5);
        dim3 grid(tiles, np);
        pairA2<<<grid, 256, 0, stream>>>(A, W, T, s);
        pairB2<<<grid, 256, 0, stream>>>(W, T, s);
    }
    form_ab<<<256, 256, 0, stream>>>(W, Ab);
    prep<<<64, 512, 0, stream>>>(W, Bv, C, V, Crows, Bbc);

    // ---- Krylov doubling (V,Crows to m=1024) + 3 extra squarings for scan ----
    const float* g = Ab;
    float* gouts[13] = {P0, P1, P0, P1, P0, P1, P0, P1, P0, GA, GB, GC, GD};
    int m = 1;
    for (int r = 0; r < 13; ++r) {
        round_kernel<<<dim3(16, 16, 3), 256, 0, stream>>>(g, gouts[r], V, Crows, m);
        g = gouts[r];
        m <<= 1;
    }

    // ---- per-chunk pieces ----
    gemm_kt<<<512, 256, 0, stream>>>(Crows, NDIM, Ab, NDIM, CrowsS, NDIM,
                                     16, NDIM, 1.f);           // CrowsS = Crows@Ab
    kv2<<<256, 256, 0, stream>>>(Crows, Bbc, kv);
    build_u<<<2048, 256, 0, stream>>>(V, x, GA, hs, U);

    // ---- Kogge-Stone scan over chunks: offsets 1,2,4,8 ----
    scan_round<<<2048, 256, 0, stream>>>(GA, U,  Z0, hs, Hmat, out + LSEQ, 1, 0);
    scan_round<<<2048, 256, 0, stream>>>(GB, Z0, Z1, hs, Hmat, out + LSEQ, 2, 0);
    scan_round<<<2048, 256, 0, stream>>>(GC, Z1, Z0, hs, Hmat, out + LSEQ, 4, 0);
    scan_round<<<2048, 256, 0, stream>>>(GD, Z0, Z1, hs, Hmat, out + LSEQ, 8, 1);

    // ---- fused epilogue ----
    emit<<<4096, 256, 0, stream>>>(CrowsS, Hmat, kv, x, out);
}